// Round 10
// baseline (12266.762 us; speedup 1.0000x reference)
//
#include <hip/hip_runtime.h>
#include <math.h>

typedef float f32x4 __attribute__((ext_vector_type(4)));

#define Bb   8
#define Tt   2048
#define Hh   1024
#define NTHR 256
#define NWG  256
#define CQ   4            // cols per WG per layer (one quad)
#define SENT 2.0f         // real h in [-1,1]; sentinel 0x7F7F7F7F = 3.39e38
#define R0   4            // fallback ring slots
#define WPL  128
#define CPW  8

// ---- primitives (semantics proven rounds 3/5/6/7/9) ----
__device__ __forceinline__ void llc_load4(f32x4& d, const float* p) {
    asm volatile("global_load_dwordx4 %0, %1, off sc0 sc1" : "=v"(d) : "v"(p));
}
__device__ __forceinline__ void llc_store1(float* p, float v) {
    asm volatile("global_store_dword %0, %1, off sc0 sc1" :: "v"(p), "v"(v) : "memory");
}
__device__ __forceinline__ void llc_store4(float* p, f32x4 v) {
    asm volatile("global_store_dwordx4 %0, %1, off sc0 sc1" :: "v"(p), "v"(v) : "memory");
}
__device__ __forceinline__ void vm0() {
    asm volatile("s_waitcnt vmcnt(0)" ::: "memory");
    __builtin_amdgcn_sched_barrier(0);   // rule #18: pin consumers after the wait
}
__device__ __forceinline__ float fast_tanh(float s) {
    const float e = __expf(2.f * s);
    return 1.f - 2.f / (e + 1.f);
}

// contiguous poll: 8 x4 slices at base + b*4 (128B); exit values are the data
__device__ __forceinline__ void pollquad(f32x4 hv[Bb], const float* base) {
    for (;;) {
        #pragma unroll
        for (int b = 0; b < Bb; ++b) llc_load4(hv[b], base + b*CQ);
        vm0();
        bool ok = true;
        #pragma unroll
        for (int b = 0; b < Bb; ++b)
            #pragma unroll
            for (int j = 0; j < 4; ++j) ok &= (hv[b][j] < SENT);
        if (__all(ok)) return;
    }
}
// strided poll (ys in d_out, layout [B][T][H])
__device__ __forceinline__ void poll8s(f32x4 hv[Bb], const float* base, size_t stride) {
    for (;;) {
        #pragma unroll
        for (int b = 0; b < Bb; ++b) llc_load4(hv[b], base + (size_t)b*stride);
        vm0();
        bool ok = true;
        #pragma unroll
        for (int b = 0; b < Bb; ++b)
            #pragma unroll
            for (int j = 0; j < 4; ++j) ok &= (hv[b][j] < SENT);
        if (__all(ok)) return;
    }
}

// 32-output butterfly over 64 lanes: in vv[o]=partial of output o (o=b*4+c);
// out: res = full-wave sum of output (lane&31) on every lane.
#define BFLY32(vv, res)                                                    \
    do {                                                                   \
        _Pragma("unroll")                                                  \
        for (int r = 0; r < 5; ++r) {                                      \
            const int bit = (lane >> r) & 1;                               \
            _Pragma("unroll")                                              \
            for (int j = 0; j < (32 >> (r + 1)); ++j) {                    \
                const float send = bit ? vv[2*j]     : vv[2*j + 1];        \
                const float mine = bit ? vv[2*j + 1] : vv[2*j];            \
                vv[j] = mine + __shfl_xor(send, 1 << r, 64);               \
            }                                                              \
        }                                                                  \
        res = vv[0] + __shfl_xor(vv[0], 32, 64);                           \
    } while (0)

// =====  primary: fused two-layer, flagless data-poll, quad history  =====
// h0 history layout: [Tt][256 quads][Bb][4] — consumer thread tid polls the
// 128B block of quad tid; producer WG wg packs+stores its quad as 8 x4s.
__global__ __launch_bounds__(NTHR, 1)
void rnn_fuse(const float* __restrict__ X,  const float* __restrict__ ihw,
              const float* __restrict__ ihb, const float* __restrict__ hhw,
              const float* __restrict__ hhb, float* __restrict__ out,
              float* __restrict__ ws)
{
    __shared__ float red0[4*32], red1[4*32];
    __builtin_amdgcn_fence(__ATOMIC_ACQUIRE, "agent");

    const int tid = threadIdx.x, lane = tid & 63, w = tid >> 6;
    const int wg  = blockIdx.x;          // owns col quad wg for BOTH layers
    const int k0  = tid * 4;
    float* hist = ws;                    // [Tt][NWG][Bb][CQ]

    // persistent weights: 4 cols x 4 k for each of {ih0, hh0, ih1, hh1}
    f32x4 wI0[CQ], wH0[CQ], wI1[CQ], wH1[CQ];
    #pragma unroll
    for (int c = 0; c < CQ; ++c) {
        const int col = wg*CQ + c;
        wI0[c] = *(const f32x4*)&ihw[(size_t)col*Hh + k0];
        wH0[c] = *(const f32x4*)&hhw[(size_t)col*Hh + k0];
        wI1[c] = *(const f32x4*)&ihw[(size_t)(Hh + col)*Hh + k0];
        wH1[c] = *(const f32x4*)&hhw[(size_t)(Hh + col)*Hh + k0];
    }
    float bias0 = 0.f, bias1 = 0.f;
    if (tid < 32) {
        const int col = wg*CQ + (tid & 3);
        bias0 = ihb[col] + hhb[col];
        bias1 = ihb[Hh + col] + hhb[Hh + col];
    }

    f32x4 xc[Bb];
    #pragma unroll
    for (int b = 0; b < Bb; ++b)
        xc[b] = *(const f32x4*)&X[((size_t)b*Tt)*Hh + k0];

    f32x4 hv[Bb];                        // h0(t-1) slice — shared by l0-hh & l1-ih

    for (int t = 0; t <= Tt; ++t) {
        const bool doL0 = (t < Tt);
        const int  u    = t - 1;         // layer-1's step this iteration

        if (doL0) {
            // l0: ih partials first (independent work while producers finish)
            float v0[32];
            #pragma unroll
            for (int c = 0; c < CQ; ++c) {
                const f32x4 wv = wI0[c];
                #pragma unroll
                for (int b = 0; b < Bb; ++b) {
                    const f32x4 x = xc[b];
                    float a = wv[0]*x[0]; a += wv[1]*x[1];
                    a += wv[2]*x[2]; a += wv[3]*x[3];
                    v0[b*CQ + c] = a;
                }
            }
            // the ONLY critical wait: h0(t-1), contiguous 128B quad
            if (t > 0) {
                pollquad(hv, hist + ((size_t)(t-1)*NWG + tid)*(Bb*CQ));
                #pragma unroll
                for (int c = 0; c < CQ; ++c) {
                    const f32x4 wv = wH0[c];
                    #pragma unroll
                    for (int b = 0; b < Bb; ++b) {
                        const f32x4 h = hv[b];
                        v0[b*CQ+c] += wv[0]*h[0]; v0[b*CQ+c] += wv[1]*h[1];
                        v0[b*CQ+c] += wv[2]*h[2]; v0[b*CQ+c] += wv[3]*h[3];
                    }
                }
            }
            float r0;
            BFLY32(v0, r0);
            if (lane < 32) red0[w*32 + lane] = r0;
            // X prefetch for t+1 (latency hidden under B1 + l1 phase)
            if (t + 1 < Tt) {
                #pragma unroll
                for (int b = 0; b < Bb; ++b)
                    xc[b] = *(const f32x4*)&X[((size_t)b*Tt + t + 1)*Hh + k0];
            }
        } else {
            // final iteration: l1 step Tt-1 still needs h0(Tt-1)
            pollquad(hv, hist + ((size_t)(Tt-1)*NWG + tid)*(Bb*CQ));
        }
        __syncthreads();                                  // B1

        // l0 combine + tanh + packed fire-and-forget publish
        if (doL0 && tid < 32) {
            const int b = tid >> 2;
            const float s = red0[tid] + red0[32+tid] + red0[64+tid]
                          + red0[96+tid] + bias0;
            const float val = fast_tanh(s);
            const float v1 = __shfl_xor(val, 1, 64);
            const float v2 = __shfl_xor(val, 2, 64);
            const float v3 = __shfl_xor(val, 3, 64);
            if ((tid & 3) == 0) {
                f32x4 pk = {val, v1, v2, v3};
                llc_store4(hist + (((size_t)t*NWG + wg)*Bb + b)*CQ, pk);
            }
            if (t == Tt-1)
                out[(size_t)Bb*Tt*Hh + (size_t)b*Hh + wg*CQ + (tid&3)] = val; // h_T[0]
        }

        // l1 step u (shadow of l0's publish->observe flight)
        if (u >= 0) {
            float v1a[32];
            #pragma unroll
            for (int c = 0; c < CQ; ++c) {                // ih on h0(u) == hv (reused!)
                const f32x4 wv = wI1[c];
                #pragma unroll
                for (int b = 0; b < Bb; ++b) {
                    const f32x4 h = hv[b];
                    float a = wv[0]*h[0]; a += wv[1]*h[1];
                    a += wv[2]*h[2]; a += wv[3]*h[3];
                    v1a[b*CQ + c] = a;
                }
            }
            if (u > 0) {                                  // hh on ys(u-1): 1 period old
                f32x4 yv[Bb];
                poll8s(yv, out + (size_t)(u-1)*Hh + k0, (size_t)Tt*Hh);
                #pragma unroll
                for (int c = 0; c < CQ; ++c) {
                    const f32x4 wv = wH1[c];
                    #pragma unroll
                    for (int b = 0; b < Bb; ++b) {
                        const f32x4 h = yv[b];
                        v1a[b*CQ+c] += wv[0]*h[0]; v1a[b*CQ+c] += wv[1]*h[1];
                        v1a[b*CQ+c] += wv[2]*h[2]; v1a[b*CQ+c] += wv[3]*h[3];
                    }
                }
            }
            float r1;
            BFLY32(v1a, r1);
            if (lane < 32) red1[w*32 + lane] = r1;
        }
        __syncthreads();                                  // B2

        if (u >= 0 && tid < 32) {
            const int b = tid >> 2;
            const float s = red1[tid] + red1[32+tid] + red1[64+tid]
                          + red1[96+tid] + bias1;
            const float val = fast_tanh(s);
            const float v1 = __shfl_xor(val, 1, 64);
            const float v2 = __shfl_xor(val, 2, 64);
            const float v3 = __shfl_xor(val, 3, 64);
            if ((tid & 3) == 0) {
                f32x4 pk = {val, v1, v2, v3};
                llc_store4(out + ((size_t)b*Tt + u)*Hh + wg*CQ, pk);  // ys(u)
            }
            if (u == Tt-1)
                out[(size_t)Bb*Tt*Hh + (size_t)(Bb + b)*Hh + wg*CQ + (tid&3)] = val; // h_T[1]
        }
    }
}

// ==========  fallback: round-5 ring kernel (proven), ws-too-small  =====
__device__ __forceinline__ void wait_ge(const unsigned long long* fq, int tid, unsigned u) {
    unsigned long long a = __hip_atomic_load(fq + tid, __ATOMIC_RELAXED,
                                             __HIP_MEMORY_SCOPE_AGENT);
    bool ok = ((unsigned)a >= u) & ((unsigned)(a >> 32) >= u);
    while (!__all(ok)) {
        __builtin_amdgcn_s_sleep(1);
        a = __hip_atomic_load(fq + tid, __ATOMIC_RELAXED, __HIP_MEMORY_SCOPE_AGENT);
        ok = ((unsigned)a >= u) & ((unsigned)(a >> 32) >= u);
    }
}
#define BUTTERFLY64()                                                      \
    do {                                                                   \
        _Pragma("unroll")                                                  \
        for (int r = 0; r < 6; ++r) {                                      \
            const int bit = (lane >> r) & 1;                               \
            _Pragma("unroll")                                              \
            for (int j = 0; j < (64 >> (r + 1)); ++j) {                    \
                const float send = bit ? vv[2*j]     : vv[2*j + 1];        \
                const float mine = bit ? vv[2*j + 1] : vv[2*j];            \
                vv[j] = mine + __shfl_xor(send, 1 << r, 64);               \
            }                                                              \
        }                                                                  \
    } while (0)

__global__ __launch_bounds__(NTHR, 1)
void rnn_persist5(const float* __restrict__ X, const float* __restrict__ ihw,
                  const float* __restrict__ ihb, const float* __restrict__ hhw,
                  const float* __restrict__ hhb, float* __restrict__ out,
                  float* __restrict__ ws)
{
    __shared__ float red[4*64];
    __shared__ float biasl[CPW];
    const int tid = threadIdx.x;
    const int wg  = blockIdx.x;
    const int lay = (wg >= WPL) ? 1 : 0;
    const int wgl = wg & (WPL-1);
    const int colbase = wgl * CPW;
    const int k0  = tid * 4;
    const int lane = tid & 63;

    float* h0ring = ws;
    float* h1ring = ws + (size_t)R0*Bb*Hh;
    unsigned* flags0 = (unsigned*)(ws + (size_t)(R0+2)*Bb*Hh);
    unsigned* flags1 = flags0 + WPL;
    const unsigned long long* f0q = (const unsigned long long*)flags0;
    const unsigned long long* f1q = (const unsigned long long*)flags1;
    unsigned* myflag = (lay ? flags1 : flags0) + wgl;

    f32x4 wAr[CPW], wBr[CPW];
    #pragma unroll
    for (int c = 0; c < CPW; ++c) {
        const int col = colbase + c;
        wAr[c] = *(const f32x4*)&ihw[((size_t)lay*Hh + col)*Hh + k0];
        wBr[c] = *(const f32x4*)&hhw[((size_t)lay*Hh + col)*Hh + k0];
    }
    if (tid < CPW) {
        const int col = colbase + tid;
        biasl[tid] = ihb[lay*Hh + col] + hhb[lay*Hh + col];
    }
    __syncthreads();

    if (lay == 0) {
        f32x4 xc[Bb];
        #pragma unroll
        for (int b = 0; b < Bb; ++b)
            xc[b] = *(const f32x4*)&X[((size_t)b*Tt)*Hh + k0];
        for (int t = 0; t < Tt; ++t) {
            float acc[CPW][Bb];
            #pragma unroll
            for (int c = 0; c < CPW; ++c) {
                const f32x4 w0 = wAr[c];
                #pragma unroll
                for (int b = 0; b < Bb; ++b) {
                    const f32x4 i0 = xc[b];
                    float a = w0[0]*i0[0]; a += w0[1]*i0[1];
                    a += w0[2]*i0[2]; a += w0[3]*i0[3];
                    acc[c][b] = a;
                }
            }
            if (tid < 64 && t > 0) {
                wait_ge(f0q, tid, (unsigned)t);
                const int tB = t - (R0 - 1);
                if (tB > 0) wait_ge(f1q, tid, (unsigned)tB);
            }
            __syncthreads();
            if (t > 0) {
                const float* hp = h0ring + (size_t)((t-1)&(R0-1))*Bb*Hh;
                f32x4 hvv[Bb];
                #pragma unroll
                for (int b = 0; b < Bb; ++b) llc_load4(hvv[b], hp + (size_t)b*Hh + k0);
                vm0();
                #pragma unroll
                for (int c = 0; c < CPW; ++c) {
                    const f32x4 w1 = wBr[c];
                    #pragma unroll
                    for (int b = 0; b < Bb; ++b) {
                        const f32x4 i1 = hvv[b];
                        acc[c][b] += w1[0]*i1[0]; acc[c][b] += w1[1]*i1[1];
                        acc[c][b] += w1[2]*i1[2]; acc[c][b] += w1[3]*i1[3];
                    }
                }
            }
            float vv[64];
            #pragma unroll
            for (int c = 0; c < CPW; ++c)
                #pragma unroll
                for (int b = 0; b < Bb; ++b) vv[b*8 + c] = acc[c][b];
            BUTTERFLY64();
            red[(tid >> 6)*64 + lane] = vv[0];
            __syncthreads();
            if (tid < 64) {
                const int b = tid >> 3, c = tid & 7;
                const float sfin = red[tid] + red[64 + tid] + red[128 + tid]
                                 + red[192 + tid] + biasl[c];
                const float val = fast_tanh(sfin);
                llc_store1(h0ring + (size_t)(t&(R0-1))*Bb*Hh + (size_t)b*Hh
                           + colbase + c, val);
                asm volatile("s_waitcnt vmcnt(0)" ::: "memory");
                if (tid == 0)
                    __hip_atomic_store(myflag, (unsigned)(t + 1),
                                       __ATOMIC_RELAXED, __HIP_MEMORY_SCOPE_AGENT);
                if (t == Tt-1)
                    out[(size_t)Bb*Tt*Hh + (size_t)b*Hh + colbase + c] = val;
            }
            const int tn = (t + 1 < Tt) ? (t + 1) : t;
            #pragma unroll
            for (int b = 0; b < Bb; ++b)
                xc[b] = *(const f32x4*)&X[((size_t)b*Tt + tn)*Hh + k0];
        }
    } else {
        for (int t = 0; t < Tt; ++t) {
            float acc[CPW][Bb];
            #pragma unroll
            for (int c = 0; c < CPW; ++c)
                #pragma unroll
                for (int b = 0; b < Bb; ++b) acc[c][b] = 0.f;
            if (t > 0) {
                if (tid < 64) wait_ge(f1q, tid, (unsigned)t);
                __syncthreads();
                const float* hp = h1ring + (size_t)((t-1)&1)*Bb*Hh;
                f32x4 hvv[Bb];
                #pragma unroll
                for (int b = 0; b < Bb; ++b) llc_load4(hvv[b], hp + (size_t)b*Hh + k0);
                vm0();
                #pragma unroll
                for (int c = 0; c < CPW; ++c) {
                    const f32x4 w1 = wBr[c];
                    #pragma unroll
                    for (int b = 0; b < Bb; ++b) {
                        const f32x4 i1 = hvv[b];
                        acc[c][b] += w1[0]*i1[0]; acc[c][b] += w1[1]*i1[1];
                        acc[c][b] += w1[2]*i1[2]; acc[c][b] += w1[3]*i1[3];
                    }
                }
            }
            if (tid < 64) wait_ge(f0q, tid, (unsigned)(t + 1));
            __syncthreads();
            {
                const float* apz = h0ring + (size_t)(t&(R0-1))*Bb*Hh;
                f32x4 av[Bb];
                #pragma unroll
                for (int b = 0; b < Bb; ++b) llc_load4(av[b], apz + (size_t)b*Hh + k0);
                vm0();
                #pragma unroll
                for (int c = 0; c < CPW; ++c) {
                    const f32x4 w0 = wAr[c];
                    #pragma unroll
                    for (int b = 0; b < Bb; ++b) {
                        const f32x4 i0 = av[b];
                        acc[c][b] += w0[0]*i0[0]; acc[c][b] += w0[1]*i0[1];
                        acc[c][b] += w0[2]*i0[2]; acc[c][b] += w0[3]*i0[3];
                    }
                }
            }
            float vv[64];
            #pragma unroll
            for (int c = 0; c < CPW; ++c)
                #pragma unroll
                for (int b = 0; b < Bb; ++b) vv[b*8 + c] = acc[c][b];
            BUTTERFLY64();
            red[(tid >> 6)*64 + lane] = vv[0];
            __syncthreads();
            if (tid < 64) {
                const int b = tid >> 3, c = tid & 7;
                const float sfin = red[tid] + red[64 + tid] + red[128 + tid]
                                 + red[192 + tid] + biasl[c];
                const float val = fast_tanh(sfin);
                llc_store1(h1ring + (size_t)(t&1)*Bb*Hh + (size_t)b*Hh
                           + colbase + c, val);
                asm volatile("s_waitcnt vmcnt(0)" ::: "memory");
                if (tid == 0)
                    __hip_atomic_store(myflag, (unsigned)(t + 1),
                                       __ATOMIC_RELAXED, __HIP_MEMORY_SCOPE_AGENT);
                out[((size_t)b*Tt + t)*Hh + colbase + c] = val;
                if (t == Tt-1)
                    out[(size_t)Bb*Tt*Hh + (size_t)(Bb + b)*Hh + colbase + c] = val;
            }
        }
    }
}

extern "C" void kernel_launch(void* const* d_in, const int* in_sizes, int n_in,
                              void* d_out, int out_size, void* d_ws, size_t ws_size,
                              hipStream_t stream) {
    const float* X   = (const float*)d_in[0];
    const float* ihw = (const float*)d_in[1];
    const float* ihb = (const float*)d_in[2];
    const float* hhw = (const float*)d_in[3];
    const float* hhb = (const float*)d_in[4];
    float* outp = (float*)d_out;
    float* wsp  = (float*)d_ws;

    const size_t hist_bytes = (size_t)Tt*NWG*Bb*CQ*sizeof(float);   // 67.1 MB

    if (ws_size >= hist_bytes) {
        // sentinel-fill the poll targets: h0 quad-history (ws) and d_out (ys)
        hipMemsetAsync(d_ws, 0x7F, hist_bytes, stream);
        hipMemsetAsync(d_out, 0x7F, (size_t)out_size*sizeof(float), stream);
        hipLaunchKernelGGL(rnn_fuse, dim3(NWG), dim3(NTHR), 0, stream,
                           X, ihw, ihb, hhw, hhb, outp, wsp);
    } else {
        const size_t zero_bytes = (size_t)(R0+2)*Bb*Hh*sizeof(float)
                                + (size_t)2*WPL*sizeof(unsigned);
        hipMemsetAsync(d_ws, 0, zero_bytes, stream);
        hipLaunchKernelGGL(rnn_persist5, dim3(NWG), dim3(NTHR), 0, stream,
                           X, ihw, ihb, hhw, hhb, outp, wsp);
    }
}

// Round 11
// 7745.385 us; speedup vs baseline: 1.5838x; 1.5838x over previous
//
#include <hip/hip_runtime.h>
#include <math.h>

typedef float f32x4 __attribute__((ext_vector_type(4)));

#define Bb   8
#define Tt   2048
#define Hh   1024
#define NTHR 256
#define NWG  256
#define CG   16           // cols per WG
#define BG   4            // batches per WG
#define SENT 2.0f         // real h in [-1,1]; sentinel 0x7F7F7F7F = 3.39e38
#define R0   4            // fallback ring slots
#define WPL  128
#define CPW  8

// ---- primitives (semantics proven rounds 3/5/6/7/9) ----
__device__ __forceinline__ void llc_load4(f32x4& d, const float* p) {
    asm volatile("global_load_dwordx4 %0, %1, off sc0 sc1" : "=v"(d) : "v"(p));
}
__device__ __forceinline__ void llc_store1(float* p, float v) {
    asm volatile("global_store_dword %0, %1, off sc0 sc1" :: "v"(p), "v"(v) : "memory");
}
__device__ __forceinline__ void llc_store4(float* p, f32x4 v) {
    asm volatile("global_store_dwordx4 %0, %1, off sc0 sc1" :: "v"(p), "v"(v) : "memory");
}
__device__ __forceinline__ void vm0() {
    asm volatile("s_waitcnt vmcnt(0)" ::: "memory");
    __builtin_amdgcn_sched_barrier(0);   // rule #18: pin consumers after the wait
}
__device__ __forceinline__ float fast_tanh(float s) {
    const float e = __expf(2.f * s);
    return 1.f - 2.f / (e + 1.f);
}

// poll 4 b-rows (16B each) at base + b*stride until all 16 dwords are real
__device__ __forceinline__ void poll4(f32x4 hv[BG], const float* base, size_t stride) {
    for (;;) {
        #pragma unroll
        for (int b = 0; b < BG; ++b) llc_load4(hv[b], base + (size_t)b*stride);
        vm0();
        bool ok = true;
        #pragma unroll
        for (int b = 0; b < BG; ++b)
            #pragma unroll
            for (int j = 0; j < 4; ++j) ok &= (hv[b][j] < SENT);
        if (__all(ok)) return;
    }
}

#define BUTTERFLY64()                                                      \
    do {                                                                   \
        _Pragma("unroll")                                                  \
        for (int r = 0; r < 6; ++r) {                                      \
            const int bit = (lane >> r) & 1;                               \
            _Pragma("unroll")                                              \
            for (int j = 0; j < (64 >> (r + 1)); ++j) {                    \
                const float send = bit ? vv[2*j]     : vv[2*j + 1];        \
                const float mine = bit ? vv[2*j + 1] : vv[2*j];            \
                vv[j] = mine + __shfl_xor(send, 1 << r, 64);               \
            }                                                              \
        }                                                                  \
    } while (0)

// ==== primary: split WG sets + batch-split (16 cols x 4 batches per WG) ====
__global__ __launch_bounds__(NTHR, 1)
void rnn_bsplit(const float* __restrict__ X,  const float* __restrict__ ihw,
                const float* __restrict__ ihb, const float* __restrict__ hhw,
                const float* __restrict__ hhb, float* __restrict__ out,
                float* __restrict__ ws)
{
    __shared__ float red[4*64];
    __builtin_amdgcn_fence(__ATOMIC_ACQUIRE, "agent");

    const int tid = threadIdx.x, lane = tid & 63, w = tid >> 6;
    const int wg  = blockIdx.x;
    const int lay = (wg >= WPL) ? 1 : 0;
    const int wgl = wg & (WPL-1);
    const int cgI = wgl & 63;            // col-group (64 per layer)
    const int bg  = wgl >> 6;            // batch-group (2 per layer)
    const int colbase = cgI * CG;
    const int b0  = bg * BG;             // first batch of this WG
    const int k0  = tid * 4;
    float* hist = ws;                    // [Tt][Bb][Hh], sentinel-filled

    // persistent weights: 16 cols x 4 k for ih and hh (32 quads = 128 VGPR)
    f32x4 wI[CG], wH[CG];
    #pragma unroll
    for (int c = 0; c < CG; ++c) {
        const int col = colbase + c;
        wI[c] = *(const f32x4*)&ihw[((size_t)lay*Hh + col)*Hh + k0];
        wH[c] = *(const f32x4*)&hhw[((size_t)lay*Hh + col)*Hh + k0];
    }
    float bias = 0.f;
    if (tid < 64) {
        const int col = colbase + (tid & 15);
        bias = ihb[lay*Hh + col] + hhb[lay*Hh + col];
    }

    if (lay == 0) {
        // ---------------- layer 0 ----------------
        f32x4 xc[BG];
        #pragma unroll
        for (int b = 0; b < BG; ++b)
            xc[b] = *(const f32x4*)&X[((size_t)(b0+b)*Tt)*Hh + k0];

        for (int t = 0; t < Tt; ++t) {
            // 1) ih partials first (independent work while producers finish)
            float vv[64];                         // o = b*16 + c
            #pragma unroll
            for (int c = 0; c < CG; ++c) {
                const f32x4 wv = wI[c];
                #pragma unroll
                for (int b = 0; b < BG; ++b) {
                    const f32x4 x = xc[b];
                    float a = wv[0]*x[0]; a += wv[1]*x[1];
                    a += wv[2]*x[2]; a += wv[3]*x[3];
                    vv[b*CG + c] = a;
                }
            }

            // 2) hh half: data-poll h0(t-1) for own 4 batches (4 x 16B)
            if (t > 0) {
                f32x4 hv[BG];
                poll4(hv, hist + ((size_t)(t-1)*Bb + b0)*Hh + k0, Hh);
                #pragma unroll
                for (int c = 0; c < CG; ++c) {
                    const f32x4 wv = wH[c];
                    #pragma unroll
                    for (int b = 0; b < BG; ++b) {
                        const f32x4 h = hv[b];
                        vv[b*CG+c] += wv[0]*h[0]; vv[b*CG+c] += wv[1]*h[1];
                        vv[b*CG+c] += wv[2]*h[2]; vv[b*CG+c] += wv[3]*h[3];
                    }
                }
            }

            // 3) reduce: butterfly (lane o -> output o) + cross-wave LDS
            BUTTERFLY64();
            red[w*64 + lane] = vv[0];
            __syncthreads();

            // 4) combine + tanh + packed fire-and-forget publish
            if (tid < 64) {
                const int b = tid >> 4, cl = tid & 15;
                const float s = red[tid] + red[64+tid] + red[128+tid]
                              + red[192+tid] + bias;
                const float val = fast_tanh(s);
                const float v1 = __shfl_xor(val, 1, 64);
                const float v2 = __shfl_xor(val, 2, 64);
                const float v3 = __shfl_xor(val, 3, 64);
                if ((tid & 3) == 0) {
                    f32x4 pk = {val, v1, v2, v3};
                    llc_store4(hist + ((size_t)t*Bb + b0 + b)*Hh + colbase + cl, pk);
                }
                if (t == Tt-1)
                    out[(size_t)Bb*Tt*Hh + (size_t)(b0+b)*Hh + colbase + cl] = val; // h_T[0]
            }

            // 5) X prefetch for t+1 (off critical path)
            const int tn = (t + 1 < Tt) ? (t + 1) : t;
            #pragma unroll
            for (int b = 0; b < BG; ++b)
                xc[b] = *(const f32x4*)&X[((size_t)(b0+b)*Tt + tn)*Hh + k0];

            __syncthreads();   // red WAR before next iteration
        }
    } else {
        // ---------------- layer 1 (h1 history IS ys in d_out) ----------------
        for (int t = 0; t < Tt; ++t) {
            float vv[64];
            #pragma unroll
            for (int o = 0; o < 64; ++o) vv[o] = 0.f;

            // stage 1: hh half — data-poll ys(t-1) (one period old, rarely spins)
            if (t > 0) {
                f32x4 yv[BG];
                poll4(yv, out + ((size_t)b0*Tt + (t-1))*Hh + k0, (size_t)Tt*Hh);
                #pragma unroll
                for (int c = 0; c < CG; ++c) {
                    const f32x4 wv = wH[c];
                    #pragma unroll
                    for (int b = 0; b < BG; ++b) {
                        const f32x4 h = yv[b];
                        vv[b*CG+c] += wv[0]*h[0]; vv[b*CG+c] += wv[1]*h[1];
                        vv[b*CG+c] += wv[2]*h[2]; vv[b*CG+c] += wv[3]*h[3];
                    }
                }
            }

            // stage 2: ih half — data-poll h0(t)
            {
                f32x4 av[BG];
                poll4(av, hist + ((size_t)t*Bb + b0)*Hh + k0, Hh);
                #pragma unroll
                for (int c = 0; c < CG; ++c) {
                    const f32x4 wv = wI[c];
                    #pragma unroll
                    for (int b = 0; b < BG; ++b) {
                        const f32x4 h = av[b];
                        vv[b*CG+c] += wv[0]*h[0]; vv[b*CG+c] += wv[1]*h[1];
                        vv[b*CG+c] += wv[2]*h[2]; vv[b*CG+c] += wv[3]*h[3];
                    }
                }
            }

            // reduce
            BUTTERFLY64();
            red[w*64 + lane] = vv[0];
            __syncthreads();

            // combine + tanh; the ys store IS the publish
            if (tid < 64) {
                const int b = tid >> 4, cl = tid & 15;
                const float s = red[tid] + red[64+tid] + red[128+tid]
                              + red[192+tid] + bias;
                const float val = fast_tanh(s);
                const float v1 = __shfl_xor(val, 1, 64);
                const float v2 = __shfl_xor(val, 2, 64);
                const float v3 = __shfl_xor(val, 3, 64);
                if ((tid & 3) == 0) {
                    f32x4 pk = {val, v1, v2, v3};
                    llc_store4(out + ((size_t)(b0+b)*Tt + t)*Hh + colbase + cl, pk);
                }
                if (t == Tt-1)
                    out[(size_t)Bb*Tt*Hh + (size_t)(Bb + b0 + b)*Hh + colbase + cl] = val; // h_T[1]
            }
            __syncthreads();   // red WAR
        }
    }
}

// ==========  fallback: round-5 ring kernel (proven), ws-too-small  =====
__device__ __forceinline__ void wait_ge(const unsigned long long* fq, int tid, unsigned u) {
    unsigned long long a = __hip_atomic_load(fq + tid, __ATOMIC_RELAXED,
                                             __HIP_MEMORY_SCOPE_AGENT);
    bool ok = ((unsigned)a >= u) & ((unsigned)(a >> 32) >= u);
    while (!__all(ok)) {
        __builtin_amdgcn_s_sleep(1);
        a = __hip_atomic_load(fq + tid, __ATOMIC_RELAXED, __HIP_MEMORY_SCOPE_AGENT);
        ok = ((unsigned)a >= u) & ((unsigned)(a >> 32) >= u);
    }
}

__global__ __launch_bounds__(NTHR, 1)
void rnn_persist5(const float* __restrict__ X, const float* __restrict__ ihw,
                  const float* __restrict__ ihb, const float* __restrict__ hhw,
                  const float* __restrict__ hhb, float* __restrict__ out,
                  float* __restrict__ ws)
{
    __shared__ float red[4*64];
    __shared__ float biasl[CPW];
    const int tid = threadIdx.x;
    const int wg  = blockIdx.x;
    const int lay = (wg >= WPL) ? 1 : 0;
    const int wgl = wg & (WPL-1);
    const int colbase = wgl * CPW;
    const int k0  = tid * 4;
    const int lane = tid & 63;

    float* h0ring = ws;
    float* h1ring = ws + (size_t)R0*Bb*Hh;
    unsigned* flags0 = (unsigned*)(ws + (size_t)(R0+2)*Bb*Hh);
    unsigned* flags1 = flags0 + WPL;
    const unsigned long long* f0q = (const unsigned long long*)flags0;
    const unsigned long long* f1q = (const unsigned long long*)flags1;
    unsigned* myflag = (lay ? flags1 : flags0) + wgl;

    f32x4 wAr[CPW], wBr[CPW];
    #pragma unroll
    for (int c = 0; c < CPW; ++c) {
        const int col = colbase + c;
        wAr[c] = *(const f32x4*)&ihw[((size_t)lay*Hh + col)*Hh + k0];
        wBr[c] = *(const f32x4*)&hhw[((size_t)lay*Hh + col)*Hh + k0];
    }
    if (tid < CPW) {
        const int col = colbase + tid;
        biasl[tid] = ihb[lay*Hh + col] + hhb[lay*Hh + col];
    }
    __syncthreads();

    if (lay == 0) {
        f32x4 xc[Bb];
        #pragma unroll
        for (int b = 0; b < Bb; ++b)
            xc[b] = *(const f32x4*)&X[((size_t)b*Tt)*Hh + k0];
        for (int t = 0; t < Tt; ++t) {
            float acc[CPW][Bb];
            #pragma unroll
            for (int c = 0; c < CPW; ++c) {
                const f32x4 w0 = wAr[c];
                #pragma unroll
                for (int b = 0; b < Bb; ++b) {
                    const f32x4 i0 = xc[b];
                    float a = w0[0]*i0[0]; a += w0[1]*i0[1];
                    a += w0[2]*i0[2]; a += w0[3]*i0[3];
                    acc[c][b] = a;
                }
            }
            if (tid < 64 && t > 0) {
                wait_ge(f0q, tid, (unsigned)t);
                const int tB = t - (R0 - 1);
                if (tB > 0) wait_ge(f1q, tid, (unsigned)tB);
            }
            __syncthreads();
            if (t > 0) {
                const float* hp = h0ring + (size_t)((t-1)&(R0-1))*Bb*Hh;
                f32x4 hvv[Bb];
                #pragma unroll
                for (int b = 0; b < Bb; ++b) llc_load4(hvv[b], hp + (size_t)b*Hh + k0);
                vm0();
                #pragma unroll
                for (int c = 0; c < CPW; ++c) {
                    const f32x4 w1 = wBr[c];
                    #pragma unroll
                    for (int b = 0; b < Bb; ++b) {
                        const f32x4 i1 = hvv[b];
                        acc[c][b] += w1[0]*i1[0]; acc[c][b] += w1[1]*i1[1];
                        acc[c][b] += w1[2]*i1[2]; acc[c][b] += w1[3]*i1[3];
                    }
                }
            }
            float vv[64];
            #pragma unroll
            for (int c = 0; c < CPW; ++c)
                #pragma unroll
                for (int b = 0; b < Bb; ++b) vv[b*8 + c] = acc[c][b];
            BUTTERFLY64();
            red[(tid >> 6)*64 + lane] = vv[0];
            __syncthreads();
            if (tid < 64) {
                const int b = tid >> 3, c = tid & 7;
                const float sfin = red[tid] + red[64 + tid] + red[128 + tid]
                                 + red[192 + tid] + biasl[c];
                const float val = fast_tanh(sfin);
                llc_store1(h0ring + (size_t)(t&(R0-1))*Bb*Hh + (size_t)b*Hh
                           + colbase + c, val);
                asm volatile("s_waitcnt vmcnt(0)" ::: "memory");
                if (tid == 0)
                    __hip_atomic_store(myflag, (unsigned)(t + 1),
                                       __ATOMIC_RELAXED, __HIP_MEMORY_SCOPE_AGENT);
                if (t == Tt-1)
                    out[(size_t)Bb*Tt*Hh + (size_t)b*Hh + colbase + c] = val;
            }
            const int tn = (t + 1 < Tt) ? (t + 1) : t;
            #pragma unroll
            for (int b = 0; b < Bb; ++b)
                xc[b] = *(const f32x4*)&X[((size_t)b*Tt + tn)*Hh + k0];
        }
    } else {
        for (int t = 0; t < Tt; ++t) {
            float acc[CPW][Bb];
            #pragma unroll
            for (int c = 0; c < CPW; ++c)
                #pragma unroll
                for (int b = 0; b < Bb; ++b) acc[c][b] = 0.f;
            if (t > 0) {
                if (tid < 64) wait_ge(f1q, tid, (unsigned)t);
                __syncthreads();
                const float* hp = h1ring + (size_t)((t-1)&1)*Bb*Hh;
                f32x4 hvv[Bb];
                #pragma unroll
                for (int b = 0; b < Bb; ++b) llc_load4(hvv[b], hp + (size_t)b*Hh + k0);
                vm0();
                #pragma unroll
                for (int c = 0; c < CPW; ++c) {
                    const f32x4 w1 = wBr[c];
                    #pragma unroll
                    for (int b = 0; b < Bb; ++b) {
                        const f32x4 i1 = hvv[b];
                        acc[c][b] += w1[0]*i1[0]; acc[c][b] += w1[1]*i1[1];
                        acc[c][b] += w1[2]*i1[2]; acc[c][b] += w1[3]*i1[3];
                    }
                }
            }
            if (tid < 64) wait_ge(f0q, tid, (unsigned)(t + 1));
            __syncthreads();
            {
                const float* apz = h0ring + (size_t)(t&(R0-1))*Bb*Hh;
                f32x4 av[Bb];
                #pragma unroll
                for (int b = 0; b < Bb; ++b) llc_load4(av[b], apz + (size_t)b*Hh + k0);
                vm0();
                #pragma unroll
                for (int c = 0; c < CPW; ++c) {
                    const f32x4 w0 = wAr[c];
                    #pragma unroll
                    for (int b = 0; b < Bb; ++b) {
                        const f32x4 i0 = av[b];
                        acc[c][b] += w0[0]*i0[0]; acc[c][b] += w0[1]*i0[1];
                        acc[c][b] += w0[2]*i0[2]; acc[c][b] += w0[3]*i0[3];
                    }
                }
            }
            float vv[64];
            #pragma unroll
            for (int c = 0; c < CPW; ++c)
                #pragma unroll
                for (int b = 0; b < Bb; ++b) vv[b*8 + c] = acc[c][b];
            BUTTERFLY64();
            red[(tid >> 6)*64 + lane] = vv[0];
            __syncthreads();
            if (tid < 64) {
                const int b = tid >> 3, c = tid & 7;
                const float sfin = red[tid] + red[64 + tid] + red[128 + tid]
                                 + red[192 + tid] + biasl[c];
                const float val = fast_tanh(sfin);
                llc_store1(h1ring + (size_t)(t&1)*Bb*Hh + (size_t)b*Hh
                           + colbase + c, val);
                asm volatile("s_waitcnt vmcnt(0)" ::: "memory");
                if (tid == 0)
                    __hip_atomic_store(myflag, (unsigned)(t + 1),
                                       __ATOMIC_RELAXED, __HIP_MEMORY_SCOPE_AGENT);
                out[((size_t)b*Tt + t)*Hh + colbase + c] = val;
                if (t == Tt-1)
                    out[(size_t)Bb*Tt*Hh + (size_t)(Bb + b)*Hh + colbase + c] = val;
            }
        }
    }
}

extern "C" void kernel_launch(void* const* d_in, const int* in_sizes, int n_in,
                              void* d_out, int out_size, void* d_ws, size_t ws_size,
                              hipStream_t stream) {
    const float* X   = (const float*)d_in[0];
    const float* ihw = (const float*)d_in[1];
    const float* ihb = (const float*)d_in[2];
    const float* hhw = (const float*)d_in[3];
    const float* hhb = (const float*)d_in[4];
    float* outp = (float*)d_out;
    float* wsp  = (float*)d_ws;

    const size_t hist_bytes = (size_t)Tt*Bb*Hh*sizeof(float);   // 67.1 MB

    if (ws_size >= hist_bytes) {
        // sentinel-fill the poll targets: h0 history (ws) and d_out (ys)
        hipMemsetAsync(d_ws, 0x7F, hist_bytes, stream);
        hipMemsetAsync(d_out, 0x7F, (size_t)out_size*sizeof(float), stream);
        hipLaunchKernelGGL(rnn_bsplit, dim3(NWG), dim3(NTHR), 0, stream,
                           X, ihw, ihb, hhw, hhb, outp, wsp);
    } else {
        const size_t zero_bytes = (size_t)(R0+2)*Bb*Hh*sizeof(float)
                                + (size_t)2*WPL*sizeof(unsigned);
        hipMemsetAsync(d_ws, 0, zero_bytes, stream);
        hipLaunchKernelGGL(rnn_persist5, dim3(NWG), dim3(NTHR), 0, stream,
                           X, ihw, ihb, hhw, hhb, outp, wsp);
    }
}